// Round 3
// baseline (498.057 us; speedup 1.0000x reference)
//
#include <hip/hip_runtime.h>

// 3x3 PCF soft-shadow — single fused kernel, 8-deep gather pipeline.
// vis[i] = (1/9) * sum_{ii,jj} sigmoid((zbuf[b, clip(y+ii), clip(x+jj)] - (depth_z[i]-BIAS)) * 1000)
//
// Per 4096-pixel chunk (one 512-thread block):
//   A: read xy (NT), build 4B records (il|x|ylow) in VGPRs, LDS histogram over
//      8 y-tiles; stage depth window into LDS (NT, coalesced).
//   B: prefix-sum (thread 0), scatter records into LDS sorted by tile
//      (rank order == ascending tile -> zbuf slab locality in L2/L3).
//   C: each thread owns 8 records. Read all 8, compute all addresses, ISSUE
//      ALL 24 GATHERS, then evaluate all 8. No loop-carried rotation — the
//      compiler collapsed 2-deep pipelines twice (VGPR_Count stuck at 24/28,
//      MLP ~3, latency-bound at 0.145 gathers/cy/CU). Full unroll + static
//      indices + __launch_bounds__(512,4) (128 VGPR cap, 2 blocks/CU) forces
//      ~8x the outstanding loads per SIMD.
//   Sigmoid: exp2 + v_rcp_f32 (exact-div chain is ~13 VALU ops, rcp path ~5).

#define SHARPNESS 1000.0f
#define BIAS 0.008f
#define S2LOG2E 1442.6950408889634f    // 1000 * log2(e)

#define S_IMG   2048
#define NBATCH  8
#define HWK     (1 << 20)
#define TSHIFT  8
#define NTILES  8                      // 2048 >> 8, 2 MiB zbuf slab per batch
#define PPB     4096                   // pixels per chunk
#define NTHR    512
#define RPT     (PPB / NTHR)           // 8 records per thread
#define NBLOCKS ((NBATCH * HWK) / PPB) // 2048
#define CPB     (HWK / PPB)            // 256 chunks per batch

typedef float f4u __attribute__((ext_vector_type(4), aligned(4)));
typedef int   i4v __attribute__((ext_vector_type(4)));

__device__ __forceinline__ float sigf(float bb, float a) {
    // sigmoid((bb - a) * 1000) = 1 / (1 + 2^((a-bb)*1000*log2e))
    const float t = (a - bb) * S2LOG2E;        // sub first: no cancellation blowup
    return __builtin_amdgcn_rcpf(1.0f + exp2f(t));
}
__device__ __forceinline__ float selv(f4u v, int s) {
    return (s == 0) ? v.x : (s == 1) ? v.y : (s == 2) ? v.z : v.w;
}

struct G9 { f4u v0, v1, v2; int x; };

__device__ __forceinline__ void g9_issue(G9& g, const float* __restrict__ zb,
                                         unsigned rec, int t) {
    const int x  = (int)((rec >> 12) & 0x7FFu);
    const int y  = (t << TSHIFT) | (int)(rec >> 23);
    const int ym = (y > 0) ? y - 1 : 0;
    const int yp = (y < S_IMG - 1) ? y + 1 : S_IMG - 1;
    const int xb = min(max(x - 1, 0), S_IMG - 4);
    const float* base = zb + xb;
    g.v0 = *(const f4u*)(base + (size_t)ym * S_IMG);
    g.v1 = *(const f4u*)(base + (size_t)y  * S_IMG);
    g.v2 = *(const f4u*)(base + (size_t)yp * S_IMG);
    g.x  = x;
}

__device__ __forceinline__ float g9_eval(const G9& g, float a) {
    if (g.x >= 1 && g.x <= S_IMG - 3) {        // interior: selectors are 0,1,2
        return sigf(g.v0.x, a) + sigf(g.v0.y, a) + sigf(g.v0.z, a)
             + sigf(g.v1.x, a) + sigf(g.v1.y, a) + sigf(g.v1.z, a)
             + sigf(g.v2.x, a) + sigf(g.v2.y, a) + sigf(g.v2.z, a);
    } else {
        const int xb = min(max(g.x - 1, 0), S_IMG - 4);
        const int s0 = max(g.x - 1, 0) - xb;
        const int s1 = g.x - xb;
        const int s2 = min(g.x + 1, S_IMG - 1) - xb;
        return sigf(selv(g.v0, s0), a) + sigf(selv(g.v0, s1), a) + sigf(selv(g.v0, s2), a)
             + sigf(selv(g.v1, s0), a) + sigf(selv(g.v1, s1), a) + sigf(selv(g.v1, s2), a)
             + sigf(selv(g.v2, s0), a) + sigf(selv(g.v2, s1), a) + sigf(selv(g.v2, s2), a);
    }
}

__global__ __launch_bounds__(NTHR, 4) void pcf_fused(
    const float* __restrict__ zbuf, const float* __restrict__ depth,
    const int* __restrict__ xy_raw, float* __restrict__ out)
{
    __shared__ float    sd[PPB];          // 16 KiB: depth in, vis out
    __shared__ unsigned srec[PPB];        // 16 KiB: records sorted by tile
    __shared__ unsigned cnt[NTILES];
    __shared__ unsigned cur[NTILES];
    __shared__ unsigned seg[NTILES + 1];

    const int g   = blockIdx.x;
    const int b   = g & (NBATCH - 1);     // batch; round-robin -> XCD-affine
    const int c   = g >> 3;
    const int tid = threadIdx.x;
    const int blk = b * CPB + c;
    const size_t pbase = (size_t)blk * PPB;
    const float* zb = zbuf + (size_t)b * ((size_t)S_IMG * S_IMG);

    if (tid < NTILES) cnt[tid] = 0;
    __syncthreads();

    // ---- Stage A: records to VGPRs + histogram; depth window to LDS ----
    unsigned rloc[RPT];
    unsigned tpack = 0;                    // 8 tiles x 3 bits
    const i4v* xy4 = (const i4v*)(xy_raw + 2 * pbase);   // 2 px per 16B
#pragma unroll
    for (int j = 0; j < RPT / 2; ++j) {
        const i4v q = __builtin_nontemporal_load(&xy4[j * NTHR + tid]);
        const int il0 = (j * NTHR + tid) * 2;
        const int t0  = q.y >> TSHIFT;
        const int t1  = q.w >> TSHIFT;
        rloc[2 * j]     = (unsigned)il0
                        | ((unsigned)q.x << 12)
                        | ((unsigned)(q.y & ((1 << TSHIFT) - 1)) << 23);
        rloc[2 * j + 1] = (unsigned)(il0 + 1)
                        | ((unsigned)q.z << 12)
                        | ((unsigned)(q.w & ((1 << TSHIFT) - 1)) << 23);
        tpack |= ((unsigned)t0 << (6 * j)) | ((unsigned)t1 << (6 * j + 3));
        atomicAdd(&cnt[t0], 1u);
        atomicAdd(&cnt[t1], 1u);
    }
    const f4u* dw = (const f4u*)(depth + pbase);
#pragma unroll
    for (int j = 0; j < PPB / (NTHR * 4); ++j)
        ((f4u*)sd)[j * NTHR + tid] = __builtin_nontemporal_load(&dw[j * NTHR + tid]);
    __syncthreads();

    // ---- Stage B: prefix + scatter into tile-sorted LDS array ----
    if (tid == 0) {
        unsigned s = 0;
#pragma unroll
        for (int t = 0; t < NTILES; ++t) { seg[t] = s; cur[t] = s; s += cnt[t]; }
        seg[NTILES] = s;                   // == PPB
    }
    __syncthreads();
#pragma unroll
    for (int j = 0; j < RPT; ++j) {
        const int t = (int)((tpack >> (3 * j)) & 7u);
        const unsigned pos = atomicAdd(&cur[t], 1u);
        srec[pos] = rloc[j];
    }
    __syncthreads();

    // segment boundaries -> registers (rank k's tile = #boundaries <= k)
    const int e1 = (int)seg[1], e2 = (int)seg[2], e3 = (int)seg[3],
              e4 = (int)seg[4], e5 = (int)seg[5], e6 = (int)seg[6],
              e7 = (int)seg[7];
#define TILE8(k) ((int)((k) >= e1) + (int)((k) >= e2) + (int)((k) >= e3) + \
                  (int)((k) >= e4) + (int)((k) >= e5) + (int)((k) >= e6) + \
                  (int)((k) >= e7))

    // ---- Stage C: all 24 gathers in flight, then evaluate ----
    {
        unsigned recv[RPT]; int ilv[RPT]; float av[RPT]; G9 gg[RPT];
#pragma unroll
        for (int i = 0; i < RPT; ++i) recv[i] = srec[i * NTHR + tid];
#pragma unroll
        for (int i = 0; i < RPT; ++i) ilv[i] = (int)(recv[i] & 0xFFFu);
#pragma unroll
        for (int i = 0; i < RPT; ++i) av[i] = sd[ilv[i]] - BIAS;
#pragma unroll
        for (int i = 0; i < RPT; ++i)
            g9_issue(gg[i], zb, recv[i], TILE8(i * NTHR + tid));
#pragma unroll
        for (int i = 0; i < RPT; ++i)
            sd[ilv[i]] = g9_eval(gg[i], av[i]) * (1.0f / 9.0f);  // slot unique per rec
    }
    __syncthreads();

    // ---- coalesced NT writeback ----
    f4u* ow = (f4u*)(out + pbase);
#pragma unroll
    for (int j = 0; j < PPB / (NTHR * 4); ++j)
        __builtin_nontemporal_store(((const f4u*)sd)[j * NTHR + tid], &ow[j * NTHR + tid]);
#undef TILE8
}

// ---------------- fallback: direct kernel ----------------
__global__ __launch_bounds__(256) void pcf_shadow_generic(
    const float* __restrict__ zbuf, const float* __restrict__ depth_z,
    const int2* __restrict__ xy, const int* __restrict__ image_size_p,
    float* __restrict__ out, int total, int zbuf_elems)
{
    const int i = blockIdx.x * blockDim.x + threadIdx.x;
    if (i >= total) return;
    const int S  = *image_size_p;
    const int SS = S * S;
    const int N  = zbuf_elems / SS;
    const int hwk = total / N;
    const int b   = i / hwk;
    const float a = depth_z[i] - BIAS;
    const int2 p  = xy[i];
    const float* base = zbuf + (size_t)b * (size_t)SS;
    float vis = 0.0f;
#pragma unroll
    for (int ii = -1; ii <= 1; ++ii) {
        const int yi = min(max(p.y + ii, 0), S - 1);
        const float* row = base + (size_t)yi * (size_t)S;
#pragma unroll
        for (int jj = -1; jj <= 1; ++jj) {
            const int xi = min(max(p.x + jj, 0), S - 1);
            vis += 1.0f / (1.0f + __expf((a - row[xi]) * SHARPNESS));
        }
    }
    out[i] = vis * (1.0f / 9.0f);
}

extern "C" void kernel_launch(void* const* d_in, const int* in_sizes, int n_in,
                              void* d_out, int out_size, void* d_ws, size_t ws_size,
                              hipStream_t stream) {
    const float* zbuf     = (const float*)d_in[0];
    const float* depth_z  = (const float*)d_in[1];
    const int*   xy_raw   = (const int*)d_in[2];
    const int*   img_size = (const int*)d_in[3];
    float*       out      = (float*)d_out;

    const int zbuf_elems = in_sizes[0];   // N*S*S
    const int total      = in_sizes[1];   // N*H*W*K

    if (zbuf_elems == NBATCH * S_IMG * S_IMG && total == NBATCH * HWK) {
        pcf_fused<<<NBLOCKS, NTHR, 0, stream>>>(zbuf, depth_z, xy_raw, out);
    } else {
        const int block = 256;
        const int grid  = (total + block - 1) / block;
        pcf_shadow_generic<<<grid, block, 0, stream>>>(zbuf, depth_z, (const int2*)xy_raw,
                                                       img_size, out, total, zbuf_elems);
    }
}

// Round 5
// 475.749 us; speedup vs baseline: 1.0469x; 1.0469x over previous
//
#include <hip/hip_runtime.h>

// 3x3 PCF soft-shadow — 2-pass, HARD phase barriers via per-tile launches.
// vis[i] = (1/9) * sum_{ii,jj} sigmoid((zbuf[b, clip(y+ii), clip(x+jj)] - (depth_z[i]-BIAS)) * 1000)
//
// Evidence across R0-R3: FETCH pinned at 0.95-1.1 GB, hbm ~3.5 TB/s, i.e.
// zbuf (128 MB) re-fetched ~7x from HBM because software tile "phases" drift
// across the grid (blocks run in ~2+ generations; nothing enforces alignment).
// R4's grid.sync() fix deadlocked the harness (cooperative launch + graph
// capture). This version gets the same phase lock from KERNEL BOUNDARIES:
//   P1: bin pixels into per-(chunk, y>>8) slabs as 4B records (il|x|ylow).
//   P2 phase t (8 launches): process every chunk's slab t. Live zbuf = one
//       2 MiB slab per batch; batch = blockIdx&7 -> XCD-affine, so each XCD's
//       gathers hit its own slab in its 4 MiB private L2. zbuf -> HBM once.
//   depth/out: scattered 4B within each chunk's private 16 KB window; lines
//   stay L3-resident across phases (depth+out = 64 MB << 256 MB L3). Plain
//   stores (NOT nontemporal) so L2/L3 merge partial lines.

#define SHARPNESS 1000.0f
#define BIAS 0.008f
#define S2LOG2E 1442.6950408889634f    // 1000 * log2(e)

#define S_IMG      2048
#define NBATCH     8
#define HWK        (1 << 20)
#define TSHIFT     8
#define NTILES     8                        // 2048 >> 8, 2 MiB slab per batch
#define PPB        4096                     // pixels per chunk
#define NBLOCKS    ((NBATCH * HWK) / PPB)   // 2048
#define CPB        (HWK / PPB)              // 256 chunks per batch
#define SLAB_CAP   768                      // mean 512, sigma ~21 -> +12 sigma
#define REC_BYTES  ((size_t)NBLOCKS * NTILES * SLAB_CAP * 4ull)   // 50.3 MB
#define WS_NEED    (REC_BYTES + (size_t)NBLOCKS * NTILES * 4ull)

typedef float f4u __attribute__((ext_vector_type(4), aligned(4)));
typedef int   i4v __attribute__((ext_vector_type(4)));

__device__ __forceinline__ float sigf(float bb, float a) {
    const float t = (a - bb) * S2LOG2E;
    return __builtin_amdgcn_rcpf(1.0f + exp2f(t));
}
__device__ __forceinline__ float selv(f4u v, int s) {
    return (s == 0) ? v.x : (s == 1) ? v.y : (s == 2) ? v.z : v.w;
}

// ---------------- Pass 1: bin 4B records into slabs ----------------
__global__ __launch_bounds__(256) void p1_bin(
    const int* __restrict__ xy_raw,
    unsigned* __restrict__ recs, unsigned* __restrict__ cnts)
{
    __shared__ unsigned cur[NTILES];
    const int blk = blockIdx.x;            // chunk id; batch = blk>>8
    const int tid = threadIdx.x;
    if (tid < NTILES) cur[tid] = 0;
    __syncthreads();

    const size_t pbase = (size_t)blk * PPB;
    const i4v* xy4 = (const i4v*)(xy_raw + 2 * pbase);   // 2 px per 16B
    unsigned* slab0 = recs + (size_t)blk * NTILES * SLAB_CAP;

#pragma unroll
    for (int j = 0; j < PPB / 512; ++j) {                // 8 iters, 2 px each
        const i4v q = __builtin_nontemporal_load(&xy4[j * 256 + tid]);
        const int il0 = (j * 256 + tid) * 2;
        const int t0  = q.y >> TSHIFT;
        const int t1  = q.w >> TSHIFT;
        const unsigned rec0 = (unsigned)il0
                            | ((unsigned)q.x << 12)
                            | ((unsigned)(q.y & ((1 << TSHIFT) - 1)) << 23);
        const unsigned rec1 = (unsigned)(il0 + 1)
                            | ((unsigned)q.z << 12)
                            | ((unsigned)(q.w & ((1 << TSHIFT) - 1)) << 23);
        const unsigned p0 = atomicAdd(&cur[t0], 1u);
        slab0[(size_t)t0 * SLAB_CAP + p0] = rec0;
        const unsigned p1 = atomicAdd(&cur[t1], 1u);
        slab0[(size_t)t1 * SLAB_CAP + p1] = rec1;
    }
    __syncthreads();
    if (tid < NTILES) cnts[blk * NTILES + tid] = cur[tid];
}

// ---------------- Pass 2, phase t: one y-tile, launch = hard barrier ----------------
struct G9 { f4u v0, v1, v2; int x; };

__device__ __forceinline__ void g9_issue(G9& g, const float* __restrict__ zb,
                                         int x, int y) {
    const int ym = (y > 0) ? y - 1 : 0;
    const int yp = (y < S_IMG - 1) ? y + 1 : S_IMG - 1;
    const int xb = min(max(x - 1, 0), S_IMG - 4);
    const float* base = zb + xb;
    g.v0 = *(const f4u*)(base + (size_t)ym * S_IMG);
    g.v1 = *(const f4u*)(base + (size_t)y  * S_IMG);
    g.v2 = *(const f4u*)(base + (size_t)yp * S_IMG);
    g.x  = x;
}

__device__ __forceinline__ float g9_eval(const G9& g, float a) {
    if (g.x >= 1 && g.x <= S_IMG - 3) {        // interior: selectors are 0,1,2
        return sigf(g.v0.x, a) + sigf(g.v0.y, a) + sigf(g.v0.z, a)
             + sigf(g.v1.x, a) + sigf(g.v1.y, a) + sigf(g.v1.z, a)
             + sigf(g.v2.x, a) + sigf(g.v2.y, a) + sigf(g.v2.z, a);
    } else {
        const int xb = min(max(g.x - 1, 0), S_IMG - 4);
        const int s0 = max(g.x - 1, 0) - xb;
        const int s1 = g.x - xb;
        const int s2 = min(g.x + 1, S_IMG - 1) - xb;
        return sigf(selv(g.v0, s0), a) + sigf(selv(g.v0, s1), a) + sigf(selv(g.v0, s2), a)
             + sigf(selv(g.v1, s0), a) + sigf(selv(g.v1, s1), a) + sigf(selv(g.v1, s2), a)
             + sigf(selv(g.v2, s0), a) + sigf(selv(g.v2, s1), a) + sigf(selv(g.v2, s2), a);
    }
}

__global__ __launch_bounds__(256, 8) void p2_phase(
    const float* __restrict__ zbuf, const float* __restrict__ depth,
    const unsigned* __restrict__ recs, const unsigned* __restrict__ cnts,
    float* __restrict__ out, int t)
{
    const int g   = blockIdx.x;
    const int b   = g & (NBATCH - 1);      // batch; round-robin -> XCD-affine:
    const int c   = g >> 3;                // XCD x gathers only batch x's slab
    const int tid = threadIdx.x;
    const int blk = b * CPB + c;           // P1 chunk id
    const size_t pbase = (size_t)blk * PPB;
    const float* zb = zbuf + (size_t)b * ((size_t)S_IMG * S_IMG);
    const float* dp = depth + pbase;
    float*       op = out + pbase;

    const int s = blk * NTILES + t;
    const int n = (int)cnts[s];
    const unsigned* slab = recs + (size_t)s * SLAB_CAP;

    for (int k = tid; k < n; k += 256) {
        const unsigned rec = slab[k];
        const int il = (int)(rec & 0xFFFu);
        const int x  = (int)((rec >> 12) & 0x7FFu);
        const int y  = (t << TSHIFT) | (int)(rec >> 23);
        const float a = dp[il] - BIAS;     // 16 KB private window: L2/L3-local
        G9 gg;
        g9_issue(gg, zb, x, y);            // slab is L2-resident this phase
        op[il] = g9_eval(gg, a) * (1.0f / 9.0f);  // plain store -> L2 merges
    }
}

// ---------------- fallback: direct kernel ----------------
__global__ __launch_bounds__(256) void pcf_shadow_generic(
    const float* __restrict__ zbuf, const float* __restrict__ depth_z,
    const int2* __restrict__ xy, const int* __restrict__ image_size_p,
    float* __restrict__ out, int total, int zbuf_elems)
{
    const int i = blockIdx.x * blockDim.x + threadIdx.x;
    if (i >= total) return;
    const int S  = *image_size_p;
    const int SS = S * S;
    const int N  = zbuf_elems / SS;
    const int hwk = total / N;
    const int b   = i / hwk;
    const float a = depth_z[i] - BIAS;
    const int2 p  = xy[i];
    const float* base = zbuf + (size_t)b * (size_t)SS;
    float vis = 0.0f;
#pragma unroll
    for (int ii = -1; ii <= 1; ++ii) {
        const int yi = min(max(p.y + ii, 0), S - 1);
        const float* row = base + (size_t)yi * (size_t)S;
#pragma unroll
        for (int jj = -1; jj <= 1; ++jj) {
            const int xi = min(max(p.x + jj, 0), S - 1);
            vis += 1.0f / (1.0f + __expf((a - row[xi]) * SHARPNESS));
        }
    }
    out[i] = vis * (1.0f / 9.0f);
}

extern "C" void kernel_launch(void* const* d_in, const int* in_sizes, int n_in,
                              void* d_out, int out_size, void* d_ws, size_t ws_size,
                              hipStream_t stream) {
    const float* zbuf     = (const float*)d_in[0];
    const float* depth_z  = (const float*)d_in[1];
    const int*   xy_raw   = (const int*)d_in[2];
    const int*   img_size = (const int*)d_in[3];
    float*       out      = (float*)d_out;

    const int zbuf_elems = in_sizes[0];   // N*S*S
    const int total      = in_sizes[1];   // N*H*W*K

    if (zbuf_elems == NBATCH * S_IMG * S_IMG && total == NBATCH * HWK &&
        ws_size >= WS_NEED) {
        unsigned* recs = (unsigned*)d_ws;
        unsigned* cnts = (unsigned*)((char*)d_ws + REC_BYTES);
        p1_bin<<<NBLOCKS, 256, 0, stream>>>(xy_raw, recs, cnts);
        for (int t = 0; t < NTILES; ++t)   // launch boundary = grid-wide barrier
            p2_phase<<<NBLOCKS, 256, 0, stream>>>(zbuf, depth_z, recs, cnts, out, t);
    } else {
        const int block = 256;
        const int grid  = (total + block - 1) / block;
        pcf_shadow_generic<<<grid, block, 0, stream>>>(zbuf, depth_z, (const int2*)xy_raw,
                                                       img_size, out, total, zbuf_elems);
    }
}

// Round 6
// 439.905 us; speedup vs baseline: 1.1322x; 1.0815x over previous
//
#include <hip/hip_runtime.h>

// 3x3 PCF soft-shadow — 2-pass, per-tile phase launches + 3-record ILP body.
// vis[i] = (1/9) * sum_{ii,jj} sigmoid((zbuf[b, clip(y+ii), clip(x+jj)] - (depth_z[i]-BIAS)) * 1000)
//
// Model (R0-R5 evidence): time ~= gathers_per_SIMD * latency / outstanding.
// All prior variants had outstanding = 8 waves x 3 gathers = 24 -> ~287 us.
// Phase launches make the per-(chunk,tile) slab exactly 512+-21 records =
// 256 thr x 2, cap 768 = x3 -> ONE straight-line 3-record body per block:
// 9 zbuf gathers + 3 depth loads all in flight before any eval, no loop
// carries to collapse, sched_barrier(0) fencing loads from evals.
// Target: VGPR 56-64 (<=64 keeps 8 blocks/CU, 32 waves/CU), W 24 -> 72.
// Phases (8 launches, t = y>>8) keep live zbuf at 16 MB (L2/L3-resident,
// XCD-affine batch = blockIdx&7), so gather latency is L2/L3-class, and
// zbuf is HBM-fetched ~once. depth/out: scattered 4B in 16 KB chunk
// windows; both 32 MB buffers stay L3-resident across phases (plain, not
// NT, so lines merge).

#define SHARPNESS 1000.0f
#define BIAS 0.008f
#define S2LOG2E 1442.6950408889634f    // 1000 * log2(e)

#define S_IMG      2048
#define NBATCH     8
#define HWK        (1 << 20)
#define TSHIFT     8
#define NTILES     8                        // 2048 >> 8, 2 MiB slab per batch
#define PPB        4096                     // pixels per chunk
#define NBLOCKS    ((NBATCH * HWK) / PPB)   // 2048
#define CPB        (HWK / PPB)              // 256 chunks per batch
#define SLAB_CAP   768                      // mean 512, sigma ~21 -> +12 sigma
#define REC_BYTES  ((size_t)NBLOCKS * NTILES * SLAB_CAP * 4ull)   // 50.3 MB
#define WS_NEED    (REC_BYTES + (size_t)NBLOCKS * NTILES * 4ull)

typedef float f4u __attribute__((ext_vector_type(4), aligned(4)));
typedef int   i4v __attribute__((ext_vector_type(4)));

__device__ __forceinline__ float sigf(float bb, float a) {
    const float t = (a - bb) * S2LOG2E;
    return __builtin_amdgcn_rcpf(1.0f + exp2f(t));
}
__device__ __forceinline__ float selv(f4u v, int s) {
    return (s == 0) ? v.x : (s == 1) ? v.y : (s == 2) ? v.z : v.w;
}

// ---------------- Pass 1: bin 4B records into slabs ----------------
__global__ __launch_bounds__(256) void p1_bin(
    const int* __restrict__ xy_raw,
    unsigned* __restrict__ recs, unsigned* __restrict__ cnts)
{
    __shared__ unsigned cur[NTILES];
    const int blk = blockIdx.x;            // chunk id; batch = blk>>8
    const int tid = threadIdx.x;
    if (tid < NTILES) cur[tid] = 0;
    __syncthreads();

    const size_t pbase = (size_t)blk * PPB;
    const i4v* xy4 = (const i4v*)(xy_raw + 2 * pbase);   // 2 px per 16B
    unsigned* slab0 = recs + (size_t)blk * NTILES * SLAB_CAP;

#pragma unroll
    for (int j = 0; j < PPB / 512; ++j) {                // 8 iters, 2 px each
        const i4v q = __builtin_nontemporal_load(&xy4[j * 256 + tid]);
        const int il0 = (j * 256 + tid) * 2;
        const int t0  = q.y >> TSHIFT;
        const int t1  = q.w >> TSHIFT;
        const unsigned rec0 = (unsigned)il0
                            | ((unsigned)q.x << 12)
                            | ((unsigned)(q.y & ((1 << TSHIFT) - 1)) << 23);
        const unsigned rec1 = (unsigned)(il0 + 1)
                            | ((unsigned)q.z << 12)
                            | ((unsigned)(q.w & ((1 << TSHIFT) - 1)) << 23);
        const unsigned p0 = atomicAdd(&cur[t0], 1u);
        slab0[(size_t)t0 * SLAB_CAP + p0] = rec0;
        const unsigned p1 = atomicAdd(&cur[t1], 1u);
        slab0[(size_t)t1 * SLAB_CAP + p1] = rec1;
    }
    __syncthreads();
    if (tid < NTILES) cnts[blk * NTILES + tid] = cur[tid];
}

// ---------------- Pass 2, phase t: straight-line 3-record body ----------------
struct G9 { f4u v0, v1, v2; int x; };

__device__ __forceinline__ void g9_issue(G9& g, const float* __restrict__ zb,
                                         int x, int y) {
    const int ym = (y > 0) ? y - 1 : 0;
    const int yp = (y < S_IMG - 1) ? y + 1 : S_IMG - 1;
    const int xb = min(max(x - 1, 0), S_IMG - 4);
    const float* base = zb + xb;
    g.v0 = *(const f4u*)(base + (size_t)ym * S_IMG);
    g.v1 = *(const f4u*)(base + (size_t)y  * S_IMG);
    g.v2 = *(const f4u*)(base + (size_t)yp * S_IMG);
    g.x  = x;
}

__device__ __forceinline__ float g9_eval(const G9& g, float a) {
    if (g.x >= 1 && g.x <= S_IMG - 3) {        // interior: selectors are 0,1,2
        return sigf(g.v0.x, a) + sigf(g.v0.y, a) + sigf(g.v0.z, a)
             + sigf(g.v1.x, a) + sigf(g.v1.y, a) + sigf(g.v1.z, a)
             + sigf(g.v2.x, a) + sigf(g.v2.y, a) + sigf(g.v2.z, a);
    } else {
        const int xb = min(max(g.x - 1, 0), S_IMG - 4);
        const int s0 = max(g.x - 1, 0) - xb;
        const int s1 = g.x - xb;
        const int s2 = min(g.x + 1, S_IMG - 1) - xb;
        return sigf(selv(g.v0, s0), a) + sigf(selv(g.v0, s1), a) + sigf(selv(g.v0, s2), a)
             + sigf(selv(g.v1, s0), a) + sigf(selv(g.v1, s1), a) + sigf(selv(g.v1, s2), a)
             + sigf(selv(g.v2, s0), a) + sigf(selv(g.v2, s1), a) + sigf(selv(g.v2, s2), a);
    }
}

__global__ __launch_bounds__(256, 8) void p2_phase(
    const float* __restrict__ zbuf, const float* __restrict__ depth,
    const unsigned* __restrict__ recs, const unsigned* __restrict__ cnts,
    float* __restrict__ out, int t)
{
    const int g   = blockIdx.x;
    const int b   = g & (NBATCH - 1);      // batch; round-robin -> XCD-affine
    const int c   = g >> 3;
    const int tid = threadIdx.x;
    const int blk = b * CPB + c;           // P1 chunk id
    const size_t pbase = (size_t)blk * PPB;
    const float* zb = zbuf + (size_t)b * ((size_t)S_IMG * S_IMG);
    const float* dp = depth + pbase;
    float*       op = out + pbase;

    const int s = blk * NTILES + t;
    const int n = (int)cnts[s];
    if (n <= 0) return;
    const int nc = n - 1;
    const unsigned* slab = recs + (size_t)s * SLAB_CAP;

    // ranks tid, tid+256, tid+512 cover n <= SLAB_CAP=768 in ONE iteration.
    // Clamped ranks do valid dummy work; stores are guarded.
    const int r0 = tid, r1 = tid + 256, r2 = tid + 512;
    const unsigned A = __builtin_nontemporal_load(&slab[min(r0, nc)]);
    const unsigned B = __builtin_nontemporal_load(&slab[min(r1, nc)]);
    const unsigned C = __builtin_nontemporal_load(&slab[min(r2, nc)]);

    const int il0 = (int)(A & 0xFFFu), il1 = (int)(B & 0xFFFu), il2 = (int)(C & 0xFFFu);
    const int x0 = (int)((A >> 12) & 0x7FFu);
    const int x1 = (int)((B >> 12) & 0x7FFu);
    const int x2 = (int)((C >> 12) & 0x7FFu);
    const int y0 = (t << TSHIFT) | (int)(A >> 23);
    const int y1 = (t << TSHIFT) | (int)(B >> 23);
    const int y2 = (t << TSHIFT) | (int)(C >> 23);

    const float a0 = dp[il0] - BIAS;       // 16 KB window: L2/L3-local
    const float a1 = dp[il1] - BIAS;
    const float a2 = dp[il2] - BIAS;

    G9 g0, g1, g2;                         // 9 gathers in flight together
    g9_issue(g0, zb, x0, y0);
    g9_issue(g1, zb, x1, y1);
    g9_issue(g2, zb, x2, y2);
    __builtin_amdgcn_sched_barrier(0);     // no eval hoisted above the loads

    const float v0 = g9_eval(g0, a0) * (1.0f / 9.0f);
    if (r0 <= nc) op[il0] = v0;            // plain store -> L2/L3 merges
    const float v1 = g9_eval(g1, a1) * (1.0f / 9.0f);
    if (r1 <= nc) op[il1] = v1;
    const float v2 = g9_eval(g2, a2) * (1.0f / 9.0f);
    if (r2 <= nc) op[il2] = v2;
}

// ---------------- fallback: direct kernel ----------------
__global__ __launch_bounds__(256) void pcf_shadow_generic(
    const float* __restrict__ zbuf, const float* __restrict__ depth_z,
    const int2* __restrict__ xy, const int* __restrict__ image_size_p,
    float* __restrict__ out, int total, int zbuf_elems)
{
    const int i = blockIdx.x * blockDim.x + threadIdx.x;
    if (i >= total) return;
    const int S  = *image_size_p;
    const int SS = S * S;
    const int N  = zbuf_elems / SS;
    const int hwk = total / N;
    const int b   = i / hwk;
    const float a = depth_z[i] - BIAS;
    const int2 p  = xy[i];
    const float* base = zbuf + (size_t)b * (size_t)SS;
    float vis = 0.0f;
#pragma unroll
    for (int ii = -1; ii <= 1; ++ii) {
        const int yi = min(max(p.y + ii, 0), S - 1);
        const float* row = base + (size_t)yi * (size_t)S;
#pragma unroll
        for (int jj = -1; jj <= 1; ++jj) {
            const int xi = min(max(p.x + jj, 0), S - 1);
            vis += 1.0f / (1.0f + __expf((a - row[xi]) * SHARPNESS));
        }
    }
    out[i] = vis * (1.0f / 9.0f);
}

extern "C" void kernel_launch(void* const* d_in, const int* in_sizes, int n_in,
                              void* d_out, int out_size, void* d_ws, size_t ws_size,
                              hipStream_t stream) {
    const float* zbuf     = (const float*)d_in[0];
    const float* depth_z  = (const float*)d_in[1];
    const int*   xy_raw   = (const int*)d_in[2];
    const int*   img_size = (const int*)d_in[3];
    float*       out      = (float*)d_out;

    const int zbuf_elems = in_sizes[0];   // N*S*S
    const int total      = in_sizes[1];   // N*H*W*K

    if (zbuf_elems == NBATCH * S_IMG * S_IMG && total == NBATCH * HWK &&
        ws_size >= WS_NEED) {
        unsigned* recs = (unsigned*)d_ws;
        unsigned* cnts = (unsigned*)((char*)d_ws + REC_BYTES);
        p1_bin<<<NBLOCKS, 256, 0, stream>>>(xy_raw, recs, cnts);
        for (int t = 0; t < NTILES; ++t)   // launch boundary = grid-wide barrier
            p2_phase<<<NBLOCKS, 256, 0, stream>>>(zbuf, depth_z, recs, cnts, out, t);
    } else {
        const int block = 256;
        const int grid  = (total + block - 1) / block;
        pcf_shadow_generic<<<grid, block, 0, stream>>>(zbuf, depth_z, (const int2*)xy_raw,
                                                       img_size, out, total, zbuf_elems);
    }
}